// Round 5
// baseline (146.305 us; speedup 1.0000x reference)
//
#include <hip/hip_runtime.h>
#include <stdint.h>

#define B_ROWS 4096
#define C_OUT  2048
#define C_IN   2048
#define EPS    1e-5f

typedef __attribute__((ext_vector_type(8))) short bf16x8;  // 8 bf16 = 4 VGPRs
typedef __attribute__((ext_vector_type(4))) float f32x4;

// RNE f32 -> bf16
__device__ __forceinline__ unsigned short f2bf(float f) {
    uint32_t u = __float_as_uint(f);
    uint32_t r = (u + 0x7fffu + ((u >> 16) & 1u)) >> 16;
    return (unsigned short)r;
}

// R11 cvt: W -> plain bf16 copy (as before). A (x) -> FRAG-MAJOR TILED bf16:
// out-block obi = r16*64 + k32 is 1 KB holding A[r16*16..+16)[k32*32..+32),
// lane l's 8 elements (row r16*16+(l&15), k k32*32+(l>>4)*8 .. +8) at
// xb + obi*512 + l*8. This IS the mfma_16x16x32 A-fragment layout -> the GEMM
// loads each A-frag as ONE fully-coalesced 16 B/lane global load (R9's
// 16-line-gather pathology gone). Writes coalesced; reads 32 B/lane row-tiled.
__global__ void cvt_f32_bf16_kernel(const float* __restrict__ x,
                                    const float* __restrict__ w,
                                    unsigned short* __restrict__ xb,
                                    unsigned short* __restrict__ wb) {
    const int b = blockIdx.x;
    const int t = threadIdx.x;
    if (b < 4096) {                       // A tiled transform: 16384 1-KB blocks
        const int obi  = b * 4 + (t >> 6);    // out-block index
        const int lane = t & 63;
        const int r16  = obi >> 6;            // 0..255
        const int k32  = obi & 63;            // 0..63
        const int row  = r16 * 16 + (lane & 15);
        const int k    = k32 * 32 + (lane >> 4) * 8;
        const float* src = x + (size_t)row * C_IN + k;
        float4 v0 = ((const float4*)src)[0];
        float4 v1 = ((const float4*)src)[1];
        bf16x8 o;
        o[0] = (short)f2bf(v0.x); o[1] = (short)f2bf(v0.y);
        o[2] = (short)f2bf(v0.z); o[3] = (short)f2bf(v0.w);
        o[4] = (short)f2bf(v1.x); o[5] = (short)f2bf(v1.y);
        o[6] = (short)f2bf(v1.z); o[7] = (short)f2bf(v1.w);
        *(bf16x8*)(xb + (size_t)obi * 512 + lane * 8) = o;
    } else {                              // W plain f32->bf16, float4-granular
        const size_t i = (size_t)(b - 4096) * 256 + t;   // < 1048576
        float4 v = ((const float4*)w)[i];
        ushort4 o;
        o.x = f2bf(v.x); o.y = f2bf(v.y); o.z = f2bf(v.z); o.w = f2bf(v.w);
        ((ushort4*)wb)[i] = o;
    }
}

// R11 gemm: R10 falsified the sync theory (43.0 ~ R8's 43.3 with half the
// barriers) -> the 176 KB/tile LDS traffic IS the wall (~65 B/cyc effective,
// at the b128 practical ceiling). Fix: A never touches LDS. cvt pre-tiles A
// into frag-major layout; A-frags load global->reg as single coalesced
// dwordx4 ops, one K-tile ahead, register-double-buffered. LDS is B-only:
//   per CU per K-tile: B-frag reads 64 KB + B-stage writes 16 KB = 80 KB
//   (~940 cyc) < MFMA floor 1242 cyc -> matrix-pipe-bound.
// A L2 locality: XCD swizzle pins 2 A-panels (2 MB) per XCD-L2; per-wave A
// stream is sequential 1-KB blocks. B: triple-buffered 3x16 KB, same verified
// granule-XOR swizzle + pre-swizzled global source.
// VMEM issue order per tile kt (pinned by sched_barrier(0)):
//   ph0: S0(kt+2) gll | A0(kt+1) x4 | MFMA(a0c,b0)
//   ph1: S1(kt+2) gll | A1(kt+1) x4 | MFMA(a1c,b1)
//   boundary: guard S(kt+1) done. Newer-than-S1(kt+1) = A1(kt)x4 [tile kt-1]
//   + S0(kt+2),A0(kt+1)x4,S1(kt+2),A1(kt+1)x4 [tile kt] = 14 -> vmcnt(14);
//   kt=30 (no stages): 4+4+4=12; prologue guard for S(t0): 10. Compiler's
//   auto-vmcnt for a-reg deps is tighter and never over-drains the stages
//   (checked: its counts leave S(kt+2) in flight). Epilogue unchanged
//   (wave's 64 cols = one GN group, per-wave shfl stats).
__global__ __launch_bounds__(512, 2)
void gemm_gn_kernel(const unsigned short* __restrict__ At,  // frag-tiled bf16
                    const unsigned short* __restrict__ W,   // [2048][2048] bf16
                    const float* __restrict__ bias,
                    const float* __restrict__ gnw,
                    const float* __restrict__ gnb,
                    float* __restrict__ out) {
    __shared__ __align__(16) unsigned short smem[3 * 8192];  // 48 KB, B only

    // XCD swizzle (bijective for 256 blocks): rr dispatch puts bid%8 on XCD
    // bid&7; each XCD gets br in {2x, 2x+1} -> its A working set = 2 MB.
    const int bid = blockIdx.x;            // 0..255
    const int xcd = bid & 7;
    const int t2  = bid >> 3;              // 0..31
    const int br  = 2 * xcd + (t2 >> 4);   // 0..15 row block (256 rows)
    const int bc  = t2 & 15;               // 0..15 col block (128 cols)

    const int tid  = threadIdx.x;     // 0..511
    const int lane = tid & 63;
    const int wave = tid >> 6;        // 0..7
    const int wr   = wave >> 1;       // 0..3 row quarter (64 rows)
    const int wc   = wave & 1;        // 0..1 col half (64 cols = 1 group)
    const int c16  = lane & 15;
    const int quad = lane >> 4;

    f32x4 acc[4][4];
#pragma unroll
    for (int i = 0; i < 4; i++)
#pragma unroll
        for (int j = 0; j < 4; j++) acc[i][j] = (f32x4){0.f, 0.f, 0.f, 0.f};

    // ---- B staging (granule-XOR swizzle, pre-swizzled global src, linear
    //      LDS dest; verified 0-conflict R4/R6/R8/R10) ----
    const int r0 = tid >> 3;                        // 0..63
    const int qo = ((tid & 7) ^ (r0 & 7)) * 8;      // element offset in row
    const unsigned short* gB = W + (size_t)(bc * 128 + r0) * C_IN + qo;
    const int t8 = tid * 8;

#define STAGE_B(dst, k0, half)                                                                      \
    __builtin_amdgcn_global_load_lds(                                                               \
        (const __attribute__((address_space(1))) void*)(gB + (size_t)((half) * 64) * C_IN + (k0)),  \
        (__attribute__((address_space(3))) void*)((dst) + (half) * 4096 + t8), 16, 0, 0)

    unsigned short* bf0 = smem;
    unsigned short* bf1 = smem + 8192;
    unsigned short* bf2 = smem + 16384;

    // B frag addressing: logical granule q at phys q ^ (c16&7)
    const int qs0 = (quad ^ (c16 & 7)) * 8;        // kk=0
    const int qs1 = ((4 + quad) ^ (c16 & 7)) * 8;  // kk=1
    int offB[4];
#pragma unroll
    for (int j = 0; j < 4; j++) offB[j] = (wc * 64 + j * 16 + c16) * 64;

    // A frag-tiled base: wave's rows start at r16 = br*16 + wr*4; frag (i,k32)
    // at + i*32768 + k32*512 elements; lane offset lane*8.
    const unsigned short* pAw = At + (size_t)(br * 16 + wr * 4) * 32768 + lane * 8;

    // ---- prologue (issue order matches steady-state ledger) ----
    bf16x8 a0c[4], a1c[4], a0n[4], a1n[4], b0[4], b1[4];
    STAGE_B(bf0, 0, 0);                           // S(t0)h0
    STAGE_B(bf0, 0, 1);                           // S(t0)h1
    STAGE_B(bf1, 64, 0);                          // S(t1)h0
#pragma unroll
    for (int i = 0; i < 4; i++) a0c[i] = *(const bf16x8*)(pAw + i * 32768 + 0 * 512);
    STAGE_B(bf1, 64, 1);                          // S(t1)h1
#pragma unroll
    for (int i = 0; i < 4; i++) a1c[i] = *(const bf16x8*)(pAw + i * 32768 + 1 * 512);
    // drain S(t0): newer = S(t1)h0 + 4A + S(t1)h1 + 4A = 10
    asm volatile("s_waitcnt vmcnt(10)" ::: "memory");
    __builtin_amdgcn_s_barrier();

    const unsigned short* pr = bf0;   // read:  B tile kt
    const unsigned short* pn = bf1;   // ready: B tile kt+1
    unsigned short*       ps = bf2;   // stage: B tile kt+2

#pragma unroll
    for (int j = 0; j < 4; j++) b0[j] = *(const bf16x8*)(pr + offB[j] + qs0);

#pragma unroll 1
    for (int kt = 0; kt < 32; ++kt) {
        const int k2 = (kt + 2) * 64;
        const int k32n = 2 * (kt + 1);

        // ---------- phase 0 ----------
#pragma unroll
        for (int j = 0; j < 4; j++) b1[j] = *(const bf16x8*)(pr + offB[j] + qs1);
        __builtin_amdgcn_sched_barrier(0);
        if (kt < 30) STAGE_B(ps, k2, 0);
        __builtin_amdgcn_sched_barrier(0);
        if (kt < 31) {
#pragma unroll
            for (int i = 0; i < 4; i++) a0n[i] = *(const bf16x8*)(pAw + i * 32768 + (size_t)k32n * 512);
        }
        __builtin_amdgcn_sched_barrier(0);
        __builtin_amdgcn_s_setprio(1);
#pragma unroll
        for (int i = 0; i < 4; i++)
#pragma unroll
            for (int j = 0; j < 4; j++)
                acc[i][j] = __builtin_amdgcn_mfma_f32_16x16x32_bf16(a0c[i], b0[j], acc[i][j], 0, 0, 0);
        __builtin_amdgcn_s_setprio(0);

        // ---------- phase 1 ----------
        if (kt < 30) STAGE_B(ps, k2, 1);
        __builtin_amdgcn_sched_barrier(0);
        if (kt < 31) {
#pragma unroll
            for (int i = 0; i < 4; i++) a1n[i] = *(const bf16x8*)(pAw + i * 32768 + (size_t)(k32n + 1) * 512);
        }
        __builtin_amdgcn_sched_barrier(0);
        __builtin_amdgcn_s_setprio(1);
#pragma unroll
        for (int i = 0; i < 4; i++)
#pragma unroll
            for (int j = 0; j < 4; j++)
                acc[i][j] = __builtin_amdgcn_mfma_f32_16x16x32_bf16(a1c[i], b1[j], acc[i][j], 0, 0, 0);
        __builtin_amdgcn_s_setprio(0);

        // ---------- boundary: guard B tile kt+1 landed ----------
        if (kt < 31) {
            if (kt < 30) asm volatile("s_waitcnt vmcnt(14)" ::: "memory");
            else         asm volatile("s_waitcnt vmcnt(12)" ::: "memory");
            __builtin_amdgcn_sched_barrier(0);
            __builtin_amdgcn_s_barrier();   // frees pr for staging; pn readable
            __builtin_amdgcn_sched_barrier(0);
#pragma unroll
            for (int j = 0; j < 4; j++) b0[j] = *(const bf16x8*)(pn + offB[j] + qs0);
        }

        // rotate buffers + A register double-buffer
        const unsigned short* tmp = pr;
        pr = pn;
        pn = ps;
        ps = (unsigned short*)tmp;
#pragma unroll
        for (int i = 0; i < 4; i++) { a0c[i] = a0n[i]; a1c[i] = a1n[i]; }
    }

    // ---- epilogue: bias + GroupNorm + hardtanh (all 8 waves, no LDS) ----
    // acc[i][j][r]: row = br*256 + wr*64 + i*16 + quad*4 + r,
    //               col = bc*128 + wc*64 + j*16 + c16. Wave's 64 cols = 1 group.
    const int colbase = bc * 128 + wc * 64;
    const int rowbase = br * 256 + wr * 64;
    float bv[4], gw[4], gb[4];
#pragma unroll
    for (int j = 0; j < 4; j++) {
        int col = colbase + j * 16 + c16;
        bv[j] = bias[col];
        gw[j] = gnw[col];
        gb[j] = gnb[col];
    }
#pragma unroll
    for (int i = 0; i < 4; i++) {
#pragma unroll
        for (int r = 0; r < 4; r++) {
            float s = 0.f, ss = 0.f;
#pragma unroll
            for (int j = 0; j < 4; j++) {
                float v = acc[i][j][r] + bv[j];
                acc[i][j][r] = v;
                s += v;
                ss += v * v;
            }
#pragma unroll
            for (int m = 1; m < 16; m <<= 1) {
                s  += __shfl_xor(s, m, 64);
                ss += __shfl_xor(ss, m, 64);
            }
            float mean = s * (1.f / 64.f);
            float var  = ss * (1.f / 64.f) - mean * mean;
            float rstd = rsqrtf(var + EPS);
            int row = rowbase + i * 16 + quad * 4 + r;
            float* orow = out + (size_t)row * C_OUT;
#pragma unroll
            for (int j = 0; j < 4; j++) {
                float v = (acc[i][j][r] - mean) * rstd * gw[j] + gb[j];
                v = fminf(1.f, fmaxf(-1.f, v));
                orow[colbase + j * 16 + c16] = v;
            }
        }
    }
}

extern "C" void kernel_launch(void* const* d_in, const int* in_sizes, int n_in,
                              void* d_out, int out_size, void* d_ws, size_t ws_size,
                              hipStream_t stream) {
    const float* x    = (const float*)d_in[0];   // [4096, 2048]
    const float* w    = (const float*)d_in[1];   // [2048, 2048]
    const float* bias = (const float*)d_in[2];   // [2048]
    const float* gnw  = (const float*)d_in[3];   // [2048]
    const float* gnb  = (const float*)d_in[4];   // [2048]
    float* out = (float*)d_out;

    unsigned short* xb = (unsigned short*)d_ws;                        // 16 MB (frag-tiled)
    unsigned short* wb = xb + (size_t)B_ROWS * C_IN;                   //  8 MB

    // grid: 4096 A-transform blocks + 4096 W-convert blocks
    cvt_f32_bf16_kernel<<<8192, 256, 0, stream>>>(x, w, xb, wb);

    gemm_gn_kernel<<<256, 512, 0, stream>>>(xb, wb, bias, gnw, gnb, out);
}

// Round 6
// 136.599 us; speedup vs baseline: 1.0711x; 1.0711x over previous
//
#include <hip/hip_runtime.h>
#include <stdint.h>

#define B_ROWS 4096
#define C_OUT  2048
#define C_IN   2048
#define EPS    1e-5f

typedef __attribute__((ext_vector_type(8))) short bf16x8;  // 8 bf16 = 4 VGPRs
typedef __attribute__((ext_vector_type(4))) float f32x4;

// RNE f32 -> bf16
__device__ __forceinline__ unsigned short f2bf(float f) {
    uint32_t u = __float_as_uint(f);
    uint32_t r = (u + 0x7fffu + ((u >> 16) & 1u)) >> 16;
    return (unsigned short)r;
}

// One launch converts both x and w (f32 -> bf16, float4-granular)
__global__ void cvt_f32_bf16_kernel(const float* __restrict__ x,
                                    const float* __restrict__ w,
                                    unsigned short* __restrict__ xb,
                                    unsigned short* __restrict__ wb,
                                    int nx4, int nw4) {
    int i = blockIdx.x * blockDim.x + threadIdx.x;
    const float* src;
    unsigned short* dst;
    if (i < nx4) {
        src = x; dst = xb;
    } else {
        i -= nx4;
        if (i >= nw4) return;
        src = w; dst = wb;
    }
    float4 v = ((const float4*)src)[i];
    ushort4 o;
    o.x = f2bf(v.x); o.y = f2bf(v.y); o.z = f2bf(v.z); o.w = f2bf(v.w);
    ((ushort4*)dst)[i] = o;
}

// R12 = revert to the session-best kernel (R0 baseline, measured 135.65 and
// 136.7 us). Session post-mortems (R7-R11):
//  - Schedule variants at this geometry (8-phase lgkm(0), counted-lgkm frag
//    dbuf, single-barrier triple-buffer) all land 43.0-46.2 us vs this
//    kernel's 41.7: the 2-barrier/2-blocks-per-CU structure's cross-block
//    wave overlap already captures what source-level pipelining adds
//    (m97-ceiling phenomenon).
//  - Data-path escapes (A global->reg, raw or pre-tiled/coalesced) measured
//    84.5 / 52.7 us: per-CU VMEM/L2 (~45-56 B/cyc) < LDS pipe (~85 B/cyc).
//  - Better bytes/FLOP geometry (128x64 waves) forces 256-col blocks ->
//    grid 128 = half the machine idle at this M,N. Unavailable.
// Fused bf16 GEMM (C = A @ W^T + bias) + GroupNorm(32 groups of 64) + hardtanh.
// 512-thread blocks, 8 waves = (row-half wr) x (col-half wc) x (K-half kh),
// each wave a 64x64 tile over half of each BK=64 slab. LDS 2x32 KB dbuf,
// grid 512 = exactly 2 blocks/CU, 16 waves/CU. Single barrier per K-iter.
// K-half combine via lane-contiguous LDS (64 KB, 0 conflicts). Swizzle
// (8 granules/row): (row,q) at q^(row&7); frag reads 2 lanes/granule = free.
__global__ __launch_bounds__(512, 4)
void gemm_gn_kernel(const unsigned short* __restrict__ A,  // [4096][2048] bf16
                    const unsigned short* __restrict__ W,  // [2048][2048] bf16
                    const float* __restrict__ bias,
                    const float* __restrict__ gnw,
                    const float* __restrict__ gnb,
                    float* __restrict__ out) {
    // buffer b at smem + b*16384: A tile (8192 shorts) then B tile (8192)
    __shared__ __align__(16) unsigned short smem[2 * 16384];  // 64 KB

    const int bc   = blockIdx.x;      // 0..15 col block (128 cols)
    const int br   = blockIdx.y;      // 0..31 row block (128 rows)
    const int t    = threadIdx.x;     // 0..511
    const int lane = t & 63;
    const int wave = t >> 6;          // 0..7
    const int wr   = wave & 1;        // row half
    const int wc   = (wave >> 1) & 1; // col half
    const int kh   = wave >> 2;       // K half (k offset kh*32 within BK=64)
    const int c16  = lane & 15;
    const int quad = lane >> 4;

    f32x4 acc[4][4];
#pragma unroll
    for (int i = 0; i < 4; i++)
#pragma unroll
        for (int j = 0; j < 4; j++) acc[i][j] = (f32x4){0.f, 0.f, 0.f, 0.f};

    // ---- staging addresses (512 threads: 2 issues for A, 2 for B) ----
    // issue n (granule G = n*512+t): row = n*64 + (t>>3), phys q' = t&7,
    // global q = (t&7)^(row&7) = (t&7)^((t>>3)&7)  (n*64 == 0 mod 8).
    const int r0 = t >> 3;                          // 0..63
    const int qo = ((t & 7) ^ (r0 & 7)) * 8;        // element offset in row
    const unsigned short* gA = A + (size_t)(br * 128 + r0) * C_IN + qo;
    const unsigned short* gB = W + (size_t)(bc * 128 + r0) * C_IN + qo;

#define STAGE(buf, k0)                                                                     \
    do {                                                                                   \
        unsigned short* sa = smem + (buf) * 16384;                                         \
        unsigned short* sb = sa + 8192;                                                    \
        _Pragma("unroll")                                                                  \
        for (int n = 0; n < 2; n++)                                                        \
            __builtin_amdgcn_global_load_lds(                                              \
                (const __attribute__((address_space(1))) void*)(gA + (size_t)(n * 64) * C_IN + (k0)), \
                (__attribute__((address_space(3))) void*)(sa + n * 4096 + t * 8), 16, 0, 0); \
        _Pragma("unroll")                                                                  \
        for (int n = 0; n < 2; n++)                                                        \
            __builtin_amdgcn_global_load_lds(                                              \
                (const __attribute__((address_space(1))) void*)(gB + (size_t)(n * 64) * C_IN + (k0)), \
                (__attribute__((address_space(3))) void*)(sb + n * 4096 + t * 8), 16, 0, 0); \
    } while (0)

    // fragment read: logical granule q = kh*4+quad lives at phys q ^ (c16&7)
    const int qs = (((kh << 2) | quad) ^ (c16 & 7)) * 8;

    STAGE(0, 0);
    int cur = 0;
    for (int it = 0; it < 32; ++it) {
        __syncthreads();   // drains buf[cur] staging; all waves done with buf[cur^1]
        if (it < 31) STAGE(cur ^ 1, (it + 1) * 64);

        const unsigned short* sa = smem + cur * 16384;
        const unsigned short* sb = sa + 8192;
        bf16x8 a[4], b[4];
#pragma unroll
        for (int i = 0; i < 4; i++)
            a[i] = *(const bf16x8*)(sa + (wr * 64 + i * 16 + c16) * 64 + qs);
#pragma unroll
        for (int j = 0; j < 4; j++)
            b[j] = *(const bf16x8*)(sb + (wc * 64 + j * 16 + c16) * 64 + qs);
#pragma unroll
        for (int i = 0; i < 4; i++)
#pragma unroll
            for (int j = 0; j < 4; j++)
                acc[i][j] = __builtin_amdgcn_mfma_f32_16x16x32_bf16(a[i], b[j], acc[i][j], 0, 0, 0);
        cur ^= 1;
    }

    // ---- combine K-halves via LDS (64 KB, exactly smem) ----
    // lane-contiguous layout: each (wave&3, i, j) slab is 64 lanes x 16 B = 1 KB
    // contiguous -> 2 lanes/bank = free (R5-verified 0 conflicts).
    __syncthreads();   // all MFMA reads of smem complete
    float* fbuf = (float*)smem;
    if (kh == 1) {
#pragma unroll
        for (int i = 0; i < 4; i++)
#pragma unroll
            for (int j = 0; j < 4; j++)
                *(f32x4*)(fbuf + (wave & 3) * 4096 + i * 1024 + j * 256 + lane * 4) = acc[i][j];
    }
    __syncthreads();
    if (kh == 1) return;   // no further barriers below
#pragma unroll
    for (int i = 0; i < 4; i++)
#pragma unroll
        for (int j = 0; j < 4; j++)
            acc[i][j] += *(const f32x4*)(fbuf + (wave & 3) * 4096 + i * 1024 + j * 256 + lane * 4);

    // ---- epilogue: bias + GroupNorm + hardtanh (kh==0 waves) ----
    // acc[i][j][r]: row = br*128 + wr*64 + i*16 + quad*4 + r,
    //               col = bc*128 + wc*64 + j*16 + c16. Wave's 64 cols = 1 group.
    const int colbase = bc * 128 + wc * 64;
    const int rowbase = br * 128 + wr * 64;
    float bv[4], gw[4], gb[4];
#pragma unroll
    for (int j = 0; j < 4; j++) {
        int col = colbase + j * 16 + c16;
        bv[j] = bias[col];
        gw[j] = gnw[col];
        gb[j] = gnb[col];
    }
#pragma unroll
    for (int i = 0; i < 4; i++) {
#pragma unroll
        for (int r = 0; r < 4; r++) {
            float s = 0.f, ss = 0.f;
#pragma unroll
            for (int j = 0; j < 4; j++) {
                float v = acc[i][j][r] + bv[j];
                acc[i][j][r] = v;
                s += v;
                ss += v * v;
            }
#pragma unroll
            for (int m = 1; m < 16; m <<= 1) {
                s  += __shfl_xor(s, m, 64);
                ss += __shfl_xor(ss, m, 64);
            }
            float mean = s * (1.f / 64.f);
            float var  = ss * (1.f / 64.f) - mean * mean;
            float rstd = rsqrtf(var + EPS);
            int row = rowbase + i * 16 + quad * 4 + r;
            float* orow = out + (size_t)row * C_OUT;
#pragma unroll
            for (int j = 0; j < 4; j++) {
                float v = (acc[i][j][r] - mean) * rstd * gw[j] + gb[j];
                v = fminf(1.f, fmaxf(-1.f, v));
                orow[colbase + j * 16 + c16] = v;
            }
        }
    }
}

extern "C" void kernel_launch(void* const* d_in, const int* in_sizes, int n_in,
                              void* d_out, int out_size, void* d_ws, size_t ws_size,
                              hipStream_t stream) {
    const float* x    = (const float*)d_in[0];   // [4096, 2048]
    const float* w    = (const float*)d_in[1];   // [2048, 2048]
    const float* bias = (const float*)d_in[2];   // [2048]
    const float* gnw  = (const float*)d_in[3];   // [2048]
    const float* gnb  = (const float*)d_in[4];   // [2048]
    float* out = (float*)d_out;

    unsigned short* xb = (unsigned short*)d_ws;                        // 16 MB
    unsigned short* wb = xb + (size_t)B_ROWS * C_IN;                   //  8 MB

    const int nx4 = B_ROWS * C_IN / 4;   // 2097152
    const int nw4 = C_OUT * C_IN / 4;    // 1048576
    cvt_f32_bf16_kernel<<<(nx4 + nw4 + 255) / 256, 256, 0, stream>>>(x, w, xb, wb, nx4, nw4);

    dim3 grid(C_OUT / 128, B_ROWS / 128);  // (16, 32) = 512 blocks = exactly 2/CU
    gemm_gn_kernel<<<grid, 512, 0, stream>>>(xb, wb, bias, gnw, gnb, out);
}